// Round 10
// baseline (10139.474 us; speedup 1.0000x reference)
//
#include <hip/hip_runtime.h>
#include <stdint.h>

#define TLEN 512
#define HDIM 512
#define DDIM 128
#define NCLS 10

typedef float f32x4 __attribute__((ext_vector_type(4)));
typedef short bf16x8 __attribute__((ext_vector_type(8)));

__device__ __forceinline__ unsigned short f2bf(float f) {
  union { float f; unsigned u; } v; v.f = f;
  return (unsigned short)((v.u + 0x7FFFu + ((v.u >> 16) & 1u)) >> 16);
}
__device__ __forceinline__ float bf2f(unsigned short h) {
  union { unsigned u; float f; } v; v.u = ((unsigned)h) << 16; return v.f;
}
__device__ __forceinline__ float sigm(float x) {
  return __builtin_amdgcn_rcpf(1.0f + __expf(-x));
}

// ---------------- gate tables: G[g][v][h], g in {f,i,c(pre-sigmoided),o} ----
__global__ void k_gates(const float* __restrict__ emb,
                        const float* __restrict__ Wfx, const float* __restrict__ bf_,
                        const float* __restrict__ Wix, const float* __restrict__ bi_,
                        const float* __restrict__ Wcx, const float* __restrict__ bc_,
                        const float* __restrict__ Wox, const float* __restrict__ bo_,
                        float* __restrict__ G) {
  int tid = blockIdx.x * 256 + threadIdx.x;          // 0..6143
  int h = tid & (HDIM - 1);
  int v = (tid >> 9) % 3;
  int g = tid / (3 * HDIM);
  const float* W; const float* bb;
  if (g == 0)      { W = Wfx; bb = bf_; }
  else if (g == 1) { W = Wix; bb = bi_; }
  else if (g == 2) { W = Wcx; bb = bc_; }
  else             { W = Wox; bb = bo_; }
  const float* e = emb + v * DDIM;
  const float* w = W + h * DDIM;
  float s = bb[h];
  #pragma unroll 8
  for (int d = 0; d < DDIM; ++d) s += e[d] * w[d];
  if (g == 2) s = sigm(s);                           // pre-sigmoid the c-gate
  G[tid] = s;
}

// ---------------- weight pack: B-fragments for mfma_f32_16x16x32_bf16 -------
// pk2 frag index: ((g_nt*2 + gate)*16 + kt)*64 + lane, 8 bf16 per frag
__global__ void k_pack_fi(const float* __restrict__ Wfh, const float* __restrict__ Wih,
                          unsigned short* __restrict__ pk) {
  int tid = blockIdx.x * 256 + threadIdx.x;          // 0..65535
  int l  = tid & 63;
  int kt = (tid >> 6) & 15;
  int g  = (tid >> 10) & 1;
  int nt = (tid >> 11) & 3;
  int hs = (tid >> 13) & 7;
  int n  = hs * 64 + nt * 16 + (l & 15);
  int k0 = kt * 32 + (l >> 4) * 8;
  const float* src = (g ? Wih : Wfh) + n * HDIM + k0;
  unsigned short* dst = pk + (size_t)tid * 8;
  #pragma unroll
  for (int e = 0; e < 8; ++e) dst[e] = f2bf(src[e]);
}

// pko frag index: (g_nt*16 + kt)*64 + lane
__global__ void k_pack_o(const float* __restrict__ Woh, unsigned short* __restrict__ pk) {
  int tid = blockIdx.x * 256 + threadIdx.x;          // 0..32767
  int l  = tid & 63;
  int kt = (tid >> 6) & 15;
  int nt = (tid >> 10) & 3;
  int hs = (tid >> 12) & 7;
  int n  = hs * 64 + nt * 16 + (l & 15);
  int k0 = kt * 32 + (l >> 4) * 8;
  const float* src = Woh + n * HDIM + k0;
  unsigned short* dst = pk + (size_t)tid * 8;
  #pragma unroll
  for (int e = 0; e < 8; ++e) dst[e] = f2bf(src[e]);
}

// ---------------- scan: 16 WGs x 1024 thr; ONE CU per 16-row batch-tile -----
// Full H=512 inside the WG: wave w owns cols [w*32, w*32+32). Weights for
// both gates live in 256 VGPRs/thread for all 512 steps. c-exchange is a
// pure LDS round-trip (2 intra-CU barriers/step). No inter-WG sync at all.
__global__ __launch_bounds__(1024, 1)
void k_scan(const int* __restrict__ x, const float* __restrict__ G,
            const unsigned short* __restrict__ pk2,
            const unsigned short* __restrict__ pko,
            unsigned short* __restrict__ hfin) {
  __shared__ unsigned short ctile[16][520];          // c_t bf16, pitch 520 (2-way banks)
  __shared__ float gts[12][520];                     // gate tables, padded pitch
  __shared__ unsigned char xv[16][512];              // token ids

  const int tid  = threadIdx.x;
  const int lane = tid & 63;
  const int w    = tid >> 6;                         // wave 0..15 -> cols [32w,32w+32)
  const int bt   = blockIdx.x;                       // batch-tile 0..15

  for (int j = tid; j < 12 * 512; j += 1024) gts[j >> 9][j & 511] = G[j];
  for (int j = tid; j < 16 * 512; j += 1024)
    xv[j >> 9][j & 511] = (unsigned char)x[(bt * 16 + (j >> 9)) * TLEN + (j & 511)];
  for (int j = tid; j < 16 * 520; j += 1024) ((unsigned short*)ctile)[j] = 0;

  // register-resident weights: 2 n-tiles x {f,i} x 16 kt
  const int nt0 = 2 * w, nt1 = 2 * w + 1;
  bf16x8 wf0[16], wi0[16], wf1[16], wi1[16];
  {
    const bf16x8* p2 = (const bf16x8*)pk2;
    const int b00 = ((nt0 * 2 + 0) * 16) * 64 + lane;
    const int b01 = ((nt0 * 2 + 1) * 16) * 64 + lane;
    const int b10 = ((nt1 * 2 + 0) * 16) * 64 + lane;
    const int b11 = ((nt1 * 2 + 1) * 16) * 64 + lane;
    #pragma unroll
    for (int kt = 0; kt < 16; ++kt) {
      wf0[kt] = p2[b00 + kt * 64];
      wi0[kt] = p2[b01 + kt * 64];
      wf1[kt] = p2[b10 + kt * 64];
      wi1[kt] = p2[b11 + kt * 64];
    }
  }

  float cf0[4] = {0.f, 0.f, 0.f, 0.f};
  float cf1[4] = {0.f, 0.f, 0.f, 0.f};
  const int rgrp = (lane >> 4) * 4;                  // C/D row base (batch row)
  const int coll = lane & 15;
  const int col0 = w * 32 + coll;
  const int col1 = w * 32 + 16 + coll;
  // A-frag read: row = lane&15, 16B chunk = lane>>4 within each kt's 64B
  const char* abase = (const char*)&ctile[0][0] + (lane & 15) * 1040 + (lane >> 4) * 16;
  const f32x4 zz = {0.f, 0.f, 0.f, 0.f};

  __syncthreads();

  for (int t = 0; t < TLEN - 1; ++t) {
    bf16x8 afr[16];
    #pragma unroll
    for (int kt = 0; kt < 16; ++kt)
      afr[kt] = *(const bf16x8*)(abase + kt * 64);   // ds_read_b128
    __syncthreads();                                 // all reads of c_t done

    f32x4 af0 = zz, ai0 = zz, af1 = zz, ai1 = zz;
    #pragma unroll
    for (int kt = 0; kt < 16; ++kt) {
      af0 = __builtin_amdgcn_mfma_f32_16x16x32_bf16(afr[kt], wf0[kt], af0, 0, 0, 0);
      ai0 = __builtin_amdgcn_mfma_f32_16x16x32_bf16(afr[kt], wi0[kt], ai0, 0, 0, 0);
      af1 = __builtin_amdgcn_mfma_f32_16x16x32_bf16(afr[kt], wf1[kt], af1, 0, 0, 0);
      ai1 = __builtin_amdgcn_mfma_f32_16x16x32_bf16(afr[kt], wi1[kt], ai1, 0, 0, 0);
    }
    #pragma unroll
    for (int r = 0; r < 4; ++r) {
      const int vv = xv[rgrp + r][t];
      {
        float fg = sigm(af0[r] + gts[0 + vv][col0]);
        float ig = sigm(ai0[r] + gts[3 + vv][col0]);
        float sc = gts[6 + vv][col0];                // pre-sigmoided c-gate
        float cn = sc * ig + cf0[r] * fg;
        cf0[r] = cn;
        ctile[rgrp + r][col0] = f2bf(cn);
      }
      {
        float fg = sigm(af1[r] + gts[0 + vv][col1]);
        float ig = sigm(ai1[r] + gts[3 + vv][col1]);
        float sc = gts[6 + vv][col1];
        float cn = sc * ig + cf1[r] * fg;
        cf1[r] = cn;
        ctile[rgrp + r][col1] = f2bf(cn);
      }
    }
    __syncthreads();                                 // c_{t+1} visible
  }

  // ---- final step t = 511: f, i and o gates; h = tanh(c)*o -----------------
  {
    const int t = TLEN - 1;
    bf16x8 afr[16];
    #pragma unroll
    for (int kt = 0; kt < 16; ++kt)
      afr[kt] = *(const bf16x8*)(abase + kt * 64);

    f32x4 af0 = zz, ai0 = zz, af1 = zz, ai1 = zz;
    #pragma unroll
    for (int kt = 0; kt < 16; ++kt) {
      af0 = __builtin_amdgcn_mfma_f32_16x16x32_bf16(afr[kt], wf0[kt], af0, 0, 0, 0);
      ai0 = __builtin_amdgcn_mfma_f32_16x16x32_bf16(afr[kt], wi0[kt], ai0, 0, 0, 0);
      af1 = __builtin_amdgcn_mfma_f32_16x16x32_bf16(afr[kt], wf1[kt], af1, 0, 0, 0);
      ai1 = __builtin_amdgcn_mfma_f32_16x16x32_bf16(afr[kt], wi1[kt], ai1, 0, 0, 0);
    }
    // o-gate: stream fragments (once; avoids +128 VGPR peak)
    f32x4 ao0 = zz, ao1 = zz;
    {
      const bf16x8* po = (const bf16x8*)pko;
      const int o0 = (nt0 * 16) * 64 + lane;
      const int o1 = (nt1 * 16) * 64 + lane;
      #pragma unroll
      for (int kt = 0; kt < 16; ++kt) {
        bf16x8 v0 = po[o0 + kt * 64];
        bf16x8 v1 = po[o1 + kt * 64];
        ao0 = __builtin_amdgcn_mfma_f32_16x16x32_bf16(afr[kt], v0, ao0, 0, 0, 0);
        ao1 = __builtin_amdgcn_mfma_f32_16x16x32_bf16(afr[kt], v1, ao1, 0, 0, 0);
      }
    }
    #pragma unroll
    for (int r = 0; r < 4; ++r) {
      const int vv = xv[rgrp + r][t];
      {
        float fg = sigm(af0[r] + gts[0 + vv][col0]);
        float ig = sigm(ai0[r] + gts[3 + vv][col0]);
        float sc = gts[6 + vv][col0];
        float cn = sc * ig + cf0[r] * fg;
        float og = sigm(ao0[r] + gts[9 + vv][col0]);
        hfin[(bt * 16 + rgrp + r) * HDIM + col0] = f2bf(tanhf(cn) * og);
      }
      {
        float fg = sigm(af1[r] + gts[0 + vv][col1]);
        float ig = sigm(ai1[r] + gts[3 + vv][col1]);
        float sc = gts[6 + vv][col1];
        float cn = sc * ig + cf1[r] * fg;
        float og = sigm(ao1[r] + gts[9 + vv][col1]);
        hfin[(bt * 16 + rgrp + r) * HDIM + col1] = f2bf(tanhf(cn) * og);
      }
    }
  }
}

// ---------------- classifier head + log_softmax: one wave per row -----------
__global__ __launch_bounds__(64)
void k_head(const unsigned short* __restrict__ hfin, const float* __restrict__ Wph,
            const float* __restrict__ bp, float* __restrict__ out) {
  const int b = blockIdx.x;
  const int lane = threadIdx.x;
  float acc[NCLS];
  #pragma unroll
  for (int c = 0; c < NCLS; ++c) acc[c] = 0.f;
  const unsigned short* hrow = hfin + (size_t)b * HDIM;
  for (int k = lane; k < HDIM; k += 64) {
    float hv = bf2f(hrow[k]);
    #pragma unroll
    for (int c = 0; c < NCLS; ++c) acc[c] += hv * Wph[c * HDIM + k];
  }
  #pragma unroll
  for (int c = 0; c < NCLS; ++c)
    #pragma unroll
    for (int off = 32; off > 0; off >>= 1)
      acc[c] += __shfl_down(acc[c], off, 64);
  if (lane == 0) {
    float p[NCLS]; float m = -1e30f;
    #pragma unroll
    for (int c = 0; c < NCLS; ++c) { p[c] = acc[c] + bp[c]; m = fmaxf(m, p[c]); }
    float s = 0.f;
    #pragma unroll
    for (int c = 0; c < NCLS; ++c) s += __expf(p[c] - m);
    const float ls = __logf(s);
    #pragma unroll
    for (int c = 0; c < NCLS; ++c) out[b * NCLS + c] = p[c] - m - ls;
  }
}

extern "C" void kernel_launch(void* const* d_in, const int* in_sizes, int n_in,
                              void* d_out, int out_size, void* d_ws, size_t ws_size,
                              hipStream_t stream) {
  const int*   x   = (const int*)d_in[0];
  const float* emb = (const float*)d_in[1];
  const float* Wfx = (const float*)d_in[2];
  const float* Wfh = (const float*)d_in[3];
  const float* bf_ = (const float*)d_in[4];
  const float* Wix = (const float*)d_in[5];
  const float* Wih = (const float*)d_in[6];
  const float* bi_ = (const float*)d_in[7];
  const float* Wox = (const float*)d_in[8];
  const float* Woh = (const float*)d_in[9];
  const float* bo_ = (const float*)d_in[10];
  const float* Wcx = (const float*)d_in[11];
  const float* bc_ = (const float*)d_in[12];
  const float* Wph = (const float*)d_in[13];
  const float* bp_ = (const float*)d_in[14];

  char* ws = (char*)d_ws;
  float*          G    = (float*)(ws);                      // 24 KB   @ 0
  unsigned short* hfin = (unsigned short*)(ws + 32768);     // 256 KB  @ 32K
  unsigned short* pk2  = (unsigned short*)(ws + 1572864);   // 1 MB    @ 1.5M
  unsigned short* pko  = (unsigned short*)(ws + 2621440);   // 512 KB  @ 2.5M

  hipLaunchKernelGGL(k_gates,   dim3(24),  dim3(256),  0, stream,
                     emb, Wfx, bf_, Wix, bi_, Wcx, bc_, Wox, bo_, G);
  hipLaunchKernelGGL(k_pack_fi, dim3(256), dim3(256),  0, stream, Wfh, Wih, pk2);
  hipLaunchKernelGGL(k_pack_o,  dim3(128), dim3(256),  0, stream, Woh, pko);
  hipLaunchKernelGGL(k_scan,    dim3(16),  dim3(1024), 0, stream, x, G, pk2, pko, hfin);
  hipLaunchKernelGGL(k_head,    dim3(256), dim3(64),   0, stream, hfin, Wph, bp_, (float*)d_out);
}

// Round 11
// 1234.253 us; speedup vs baseline: 8.2151x; 8.2151x over previous
//
#include <hip/hip_runtime.h>
#include <stdint.h>

#define TLEN 512
#define HDIM 512
#define DDIM 128
#define NCLS 10

typedef float f32x4 __attribute__((ext_vector_type(4)));
typedef short bf16x8 __attribute__((ext_vector_type(8)));
typedef unsigned long long u64;

__device__ __forceinline__ unsigned short f2bf(float f) {
  union { float f; unsigned u; } v; v.f = f;
  return (unsigned short)((v.u + 0x7FFFu + ((v.u >> 16) & 1u)) >> 16);
}
__device__ __forceinline__ float bf2f(unsigned short h) {
  union { unsigned u; float f; } v; v.u = ((unsigned)h) << 16; return v.f;
}
__device__ __forceinline__ float sigm(float x) {
  return __builtin_amdgcn_rcpf(1.0f + __expf(-x));
}
__device__ __forceinline__ void ast16(unsigned short* p, unsigned short v) {
  __hip_atomic_store(p, v, __ATOMIC_RELAXED, __HIP_MEMORY_SCOPE_AGENT);
}
__device__ __forceinline__ void astd(unsigned* p, unsigned v) {
  __hip_atomic_store(p, v, __ATOMIC_RELAXED, __HIP_MEMORY_SCOPE_AGENT);
}
__device__ __forceinline__ unsigned aldd(const unsigned* p) {
  return __hip_atomic_load(p, __ATOMIC_RELAXED, __HIP_MEMORY_SCOPE_AGENT);
}

// agent-scope (MALL) batched 16B load — proven correct (R9 passed with these)
#define GLOAD_SC1(dst, addr) \
  asm volatile("global_load_dwordx4 %0, %1, off sc1" : "=&v"(dst) : "v"(addr))
// XCD-L2 load: bypass L1, served by the shared per-XCD L2
#define GLOAD_SC0(dst, addr) \
  asm volatile("global_load_dwordx4 %0, %1, off sc0" : "=&v"(dst) : "v"(addr))
// XCD-L2 stores (write into the shared L2 — same-XCD coherence point)
#define GSTORE16_SC0(addr, val) \
  asm volatile("global_store_short %0, %1, off sc0" :: "v"(addr), "v"(val) : "memory")
#define GSTORED_SC0(addr, val) \
  asm volatile("global_store_dword %0, %1, off sc0" :: "v"(addr), "v"(val) : "memory")
#define VMWAIT() do { asm volatile("s_waitcnt vmcnt(0)" ::: "memory"); \
                      __builtin_amdgcn_sched_barrier(0); } while (0)

// ---------------- gate tables: G[g][v][h], g in {f,i,c(pre-sigmoided),o} ----
__global__ void k_gates(const float* __restrict__ emb,
                        const float* __restrict__ Wfx, const float* __restrict__ bf_,
                        const float* __restrict__ Wix, const float* __restrict__ bi_,
                        const float* __restrict__ Wcx, const float* __restrict__ bc_,
                        const float* __restrict__ Wox, const float* __restrict__ bo_,
                        float* __restrict__ G) {
  int tid = blockIdx.x * 256 + threadIdx.x;          // 0..6143
  int h = tid & (HDIM - 1);
  int v = (tid >> 9) % 3;
  int g = tid / (3 * HDIM);
  const float* W; const float* bb;
  if (g == 0)      { W = Wfx; bb = bf_; }
  else if (g == 1) { W = Wix; bb = bi_; }
  else if (g == 2) { W = Wcx; bb = bc_; }
  else             { W = Wox; bb = bo_; }
  const float* e = emb + v * DDIM;
  const float* w = W + h * DDIM;
  float s = bb[h];
  #pragma unroll 8
  for (int d = 0; d < DDIM; ++d) s += e[d] * w[d];
  if (g == 2) s = sigm(s);                           // pre-sigmoid the c-gate
  G[tid] = s;
}

// ---------------- weight pack: register-resident B-fragments ----------------
// pk2: [hs(8)][nt(4)][gate(2)][kt(16)][lane(64)][e(8)] bf16
__global__ void k_pack_fi(const float* __restrict__ Wfh, const float* __restrict__ Wih,
                          unsigned short* __restrict__ pk) {
  int tid = blockIdx.x * 256 + threadIdx.x;          // 0..65535
  int l  = tid & 63;
  int kt = (tid >> 6) & 15;
  int g  = (tid >> 10) & 1;
  int nt = (tid >> 11) & 3;
  int hs = (tid >> 13) & 7;
  int n  = hs * 64 + nt * 16 + (l & 15);
  int k0 = kt * 32 + (l >> 4) * 8;
  const float* src = (g ? Wih : Wfh) + n * HDIM + k0;
  unsigned short* dst = pk + (size_t)tid * 8;
  #pragma unroll
  for (int e = 0; e < 8; ++e) dst[e] = f2bf(src[e]);
}

// pko: [hs(8)][nt(4)][kt(16)][lane(64)][e(8)] bf16
__global__ void k_pack_o(const float* __restrict__ Woh, unsigned short* __restrict__ pk) {
  int tid = blockIdx.x * 256 + threadIdx.x;          // 0..32767
  int l  = tid & 63;
  int kt = (tid >> 6) & 15;
  int nt = (tid >> 10) & 3;
  int hs = (tid >> 12) & 7;
  int n  = hs * 64 + nt * 16 + (l & 15);
  int k0 = kt * 32 + (l >> 4) * 8;
  const float* src = Woh + n * HDIM + k0;
  unsigned short* dst = pk + (size_t)tid * 8;
  #pragma unroll
  for (int e = 0; e < 8; ++e) dst[e] = f2bf(src[e]);
}

// ---------------- scan: 128 WGs = 16 batch-tiles x 8 h-slices ---------------
// R4 skeleton. Producers write c + flags to BOTH a sc0 (XCD-L2) copy and the
// proven sc1 (MALL) copy. Consumers try a bounded sc0 poll (peers share an
// XCD per probe); on timeout they stick to the proven sc1 path forever.
__global__ __launch_bounds__(256, 1)
void k_scan(const int* __restrict__ x, const float* __restrict__ G,
            const unsigned short* __restrict__ pk2,
            const unsigned short* __restrict__ pko,
            char* __restrict__ bufB, unsigned* __restrict__ flgB,
            char* __restrict__ bufA, unsigned* __restrict__ flgA,
            unsigned* __restrict__ xcdtab,
            unsigned short* __restrict__ hfin) {
  __shared__ float gts[12][68];
  __shared__ unsigned char xv[16][516];
  __shared__ uint4 lds_a[16][64];                    // A-frag share (16 KB)
  __shared__ int fastsh, fastok;

  const int tid  = threadIdx.x;
  const int lane = tid & 63;
  const int w    = tid >> 6;                         // wave = nt (0..3)
  const int bt   = blockIdx.x & 15;
  const int hs   = blockIdx.x >> 4;

  // ---- placement probe (proven agent-scope ops only) -----------------------
  if (tid == 0) {
    unsigned myx;
    asm volatile("s_getreg_b32 %0, hwreg(HW_REG_XCC_ID)" : "=s"(myx));
    astd(xcdtab + (hs * 16 + bt), (myx & 0xFFu) | 0x100u);
    unsigned id0 = 0; int f = 1;
    for (int k = 0; k < 8; ++k) {
      unsigned v;
      do { v = aldd(xcdtab + (k * 16 + bt)); } while (!(v & 0x100u));
      if (k == 0) id0 = v; else f &= (v == id0);
    }
    fastsh = f; fastok = f;
  }

  for (int jj = tid; jj < 12 * 64; jj += 256) {
    int gv = jj >> 6, c = jj & 63;
    gts[gv][c] = G[gv * HDIM + hs * 64 + c];
  }
  for (int jj = tid; jj < 16 * TLEN; jj += 256) {
    int r = jj >> 9, tt = jj & (TLEN - 1);
    xv[r][tt] = (unsigned char)x[(bt * 16 + r) * TLEN + tt];
  }

  bf16x8 wf[16], wi[16];
  {
    const bf16x8* ws = (const bf16x8*)pk2 + (size_t)((hs * 4 + w) * 2) * (16 * 64) + lane;
    #pragma unroll
    for (int kt = 0; kt < 16; ++kt) { wf[kt] = ws[kt * 64]; wi[kt] = ws[(16 + kt) * 64]; }
  }

  bf16x8 afr[16];
  #pragma unroll
  for (int kt = 0; kt < 16; ++kt) afr[kt] = bf16x8{0,0,0,0,0,0,0,0};  // c_0 = 0

  float cf[4] = {0.f, 0.f, 0.f, 0.f};
  const int rgrp = (lane >> 4) * 4;                  // C/D row base (batch row)
  const int coll = lane & 15;                        // C/D col (within 16-tile)
  const int col  = w * 16 + coll;                    // h col within slice
  const int colb = (hs * 64 + col) * 2;              // byte offset within a row
  const int rowb = (lane & 15) * 1024 + (lane >> 4) * 16;
  const f32x4 zz = {0.f, 0.f, 0.f, 0.f};

  __syncthreads();

  for (int t = 0; t < TLEN - 1; ++t) {
    f32x4 af = zz, ai = zz;
    #pragma unroll
    for (int kt = 0; kt < 16; ++kt) {
      af = __builtin_amdgcn_mfma_f32_16x16x32_bf16(afr[kt], wf[kt], af, 0, 0, 0);
      ai = __builtin_amdgcn_mfma_f32_16x16x32_bf16(afr[kt], wi[kt], ai, 0, 0, 0);
    }
    const unsigned tg = (unsigned)(t + 1);
    const int par = (int)(tg & 1);
    char* dbB = bufB + par * 262144 + bt * 16384;
    char* dbA = bufA + par * 262144 + bt * 16384;
    const bool tryfast = (fastok != 0);              // read before barriers below

    #pragma unroll
    for (int r = 0; r < 4; ++r) {
      int vv = xv[rgrp + r][t];
      float fg = sigm(af[r] + gts[0 + vv][col]);
      float ig = sigm(ai[r] + gts[3 + vv][col]);
      float sc = gts[6 + vv][col];                   // pre-sigmoided c-gate
      float cn = sc * ig + cf[r] * fg;
      cf[r] = cn;
      unsigned short hv = f2bf(cn);
      ast16((unsigned short*)(dbB + (rgrp + r) * 1024 + colb), hv);
      GSTORE16_SC0(dbA + (rgrp + r) * 1024 + colb, (unsigned)hv);
    }
    __syncthreads();                                 // both copies drained (vmcnt 0)

    unsigned* flB = flgB + (par * 16 + bt) * 16;     // 64B line, dword per hs
    unsigned* flA = flgA + (par * 16 + bt) * 16;
    if (tid == 0) {
      GSTORED_SC0(flA + hs, tg);
      astd(flB + hs, tg);
    }

    // ---- flag wait: bounded sc0 (XCD-L2), sticky fallback to sc1 (MALL) ----
    uint4 f0, f1;
    bool ok = false;
    if (tryfast) {
      for (int it = 0; it < 24; ++it) {
        GLOAD_SC0(f0, (const char*)flA); GLOAD_SC0(f1, (const char*)flA + 16); VMWAIT();
        if (((f0.x ^ tg) | (f0.y ^ tg) | (f0.z ^ tg) | (f0.w ^ tg) |
             (f1.x ^ tg) | (f1.y ^ tg) | (f1.z ^ tg) | (f1.w ^ tg)) == 0u) {
          ok = true; break;
        }
      }
      if (!ok && lane == 0) fastok = 0;              // sticky degrade
    }
    if (!ok) {
      do { GLOAD_SC1(f0, (const char*)flB); GLOAD_SC1(f1, (const char*)flB + 16); VMWAIT(); }
      while (((f0.x ^ tg) | (f0.y ^ tg) | (f0.z ^ tg) | (f0.w ^ tg) |
              (f1.x ^ tg) | (f1.y ^ tg) | (f1.z ^ tg) | (f1.w ^ tg)) != 0u);
    }

    // ---- batched data loads: this wave's 4 kt quarters (full 64B lines) ----
    uint4 q0, q1, q2, q3;
    if (ok) {
      const char* rb = dbA + rowb + (w << 8);
      GLOAD_SC0(q0, rb);       GLOAD_SC0(q1, rb + 64);
      GLOAD_SC0(q2, rb + 128); GLOAD_SC0(q3, rb + 192);
    } else {
      const char* rb = dbB + rowb + (w << 8);
      GLOAD_SC1(q0, rb);       GLOAD_SC1(q1, rb + 64);
      GLOAD_SC1(q2, rb + 128); GLOAD_SC1(q3, rb + 192);
    }
    VMWAIT();
    lds_a[(w << 2) | 0][lane] = q0;
    lds_a[(w << 2) | 1][lane] = q1;
    lds_a[(w << 2) | 2][lane] = q2;
    lds_a[(w << 2) | 3][lane] = q3;
    __syncthreads();
    #pragma unroll
    for (int kt = 0; kt < 16; ++kt) {
      union { uint4 q; bf16x8 v; } u;
      u.q = lds_a[kt][lane];
      afr[kt] = u.v;
    }
  }

  // ---- final step t = 511: f, i and o gates; h = tanh(c)*o -----------------
  {
    const int t = TLEN - 1;
    f32x4 af = zz, ai = zz, ao = zz;
    #pragma unroll
    for (int kt = 0; kt < 16; ++kt) {
      af = __builtin_amdgcn_mfma_f32_16x16x32_bf16(afr[kt], wf[kt], af, 0, 0, 0);
      ai = __builtin_amdgcn_mfma_f32_16x16x32_bf16(afr[kt], wi[kt], ai, 0, 0, 0);
    }
    bf16x8 wo[16];
    const bf16x8* os = (const bf16x8*)pko + (size_t)(hs * 4 + w) * (16 * 64) + lane;
    #pragma unroll
    for (int kt = 0; kt < 16; ++kt) wo[kt] = os[kt * 64];
    #pragma unroll
    for (int kt = 0; kt < 16; ++kt)
      ao = __builtin_amdgcn_mfma_f32_16x16x32_bf16(afr[kt], wo[kt], ao, 0, 0, 0);
    #pragma unroll
    for (int r = 0; r < 4; ++r) {
      int vv = xv[rgrp + r][t];
      float fg = sigm(af[r] + gts[0 + vv][col]);
      float ig = sigm(ai[r] + gts[3 + vv][col]);
      float sc = gts[6 + vv][col];
      float cn = sc * ig + cf[r] * fg;
      float og = sigm(ao[r] + gts[9 + vv][col]);
      float hv = tanhf(cn) * og;
      hfin[(bt * 16 + rgrp + r) * HDIM + hs * 64 + col] = f2bf(hv);
    }
  }
}

// ---------------- classifier head + log_softmax: one wave per row -----------
__global__ __launch_bounds__(64)
void k_head(const unsigned short* __restrict__ hfin, const float* __restrict__ Wph,
            const float* __restrict__ bp, float* __restrict__ out) {
  const int b = blockIdx.x;
  const int lane = threadIdx.x;
  float acc[NCLS];
  #pragma unroll
  for (int c = 0; c < NCLS; ++c) acc[c] = 0.f;
  const unsigned short* hrow = hfin + (size_t)b * HDIM;
  for (int k = lane; k < HDIM; k += 64) {
    float hv = bf2f(hrow[k]);
    #pragma unroll
    for (int c = 0; c < NCLS; ++c) acc[c] += hv * Wph[c * HDIM + k];
  }
  #pragma unroll
  for (int c = 0; c < NCLS; ++c)
    #pragma unroll
    for (int off = 32; off > 0; off >>= 1)
      acc[c] += __shfl_down(acc[c], off, 64);
  if (lane == 0) {
    float p[NCLS]; float m = -1e30f;
    #pragma unroll
    for (int c = 0; c < NCLS; ++c) { p[c] = acc[c] + bp[c]; m = fmaxf(m, p[c]); }
    float s = 0.f;
    #pragma unroll
    for (int c = 0; c < NCLS; ++c) s += __expf(p[c] - m);
    const float ls = __logf(s);
    #pragma unroll
    for (int c = 0; c < NCLS; ++c) out[b * NCLS + c] = p[c] - m - ls;
  }
}

extern "C" void kernel_launch(void* const* d_in, const int* in_sizes, int n_in,
                              void* d_out, int out_size, void* d_ws, size_t ws_size,
                              hipStream_t stream) {
  const int*   x   = (const int*)d_in[0];
  const float* emb = (const float*)d_in[1];
  const float* Wfx = (const float*)d_in[2];
  const float* Wfh = (const float*)d_in[3];
  const float* bf_ = (const float*)d_in[4];
  const float* Wix = (const float*)d_in[5];
  const float* Wih = (const float*)d_in[6];
  const float* bi_ = (const float*)d_in[7];
  const float* Wox = (const float*)d_in[8];
  const float* Woh = (const float*)d_in[9];
  const float* bo_ = (const float*)d_in[10];
  const float* Wcx = (const float*)d_in[11];
  const float* bc_ = (const float*)d_in[12];
  const float* Wph = (const float*)d_in[13];
  const float* bp_ = (const float*)d_in[14];

  char* ws = (char*)d_ws;
  float*          G      = (float*)(ws);                    // 24 KB  @ 0
  unsigned*       flgB   = (unsigned*)(ws + 24576);         // 2 KB   @ 24K
  unsigned*       flgA   = (unsigned*)(ws + 26624);         // 2 KB   @ 26K
  unsigned*       xcdtab = (unsigned*)(ws + 28672);         // 512 B  @ 28K
  unsigned short* hfin   = (unsigned short*)(ws + 32768);   // 256 KB @ 32K
  char*           bufA   = (char*)(ws + 327680);            // 512 KB @ 320K
  char*           bufB   = (char*)(ws + 1048576);           // 512 KB @ 1M
  unsigned short* pk2    = (unsigned short*)(ws + 1572864); // 1 MB   @ 1.5M
  unsigned short* pko    = (unsigned short*)(ws + 2621440); // 512 KB @ 2.5M

  hipMemsetAsync(flgB, 0, 8192, stream);                    // flags A/B + xcdtab fresh
  hipLaunchKernelGGL(k_gates,   dim3(24),  dim3(256), 0, stream,
                     emb, Wfx, bf_, Wix, bi_, Wcx, bc_, Wox, bo_, G);
  hipLaunchKernelGGL(k_pack_fi, dim3(256), dim3(256), 0, stream, Wfh, Wih, pk2);
  hipLaunchKernelGGL(k_pack_o,  dim3(128), dim3(256), 0, stream, Woh, pko);
  hipLaunchKernelGGL(k_scan,    dim3(128), dim3(256), 0, stream,
                     x, G, pk2, pko, bufB, flgB, bufA, flgA, xcdtab, hfin);
  hipLaunchKernelGGL(k_head,    dim3(256), dim3(64),  0, stream, hfin, Wph, bp_, (float*)d_out);
}